// Round 1
// baseline (67.304 us; speedup 1.0000x reference)
//
#include <hip/hip_runtime.h>

// QRNN fused kernel for MI355X.
// Shapes: B=64, S=2048, VOCAB=128, HIDDEN=256, gates=768, emb_dim=124, num=7.
//
// Strategy:
//  - Precompute G[128][768] = W_conv[:, :124] @ emb_table.T + b_conv + W_conv[:,124:]@b_num
//    and Wg_t[7][768] = (W_conv[:,124:] @ W_num) transposed for coalesced reads.
//  - Main scan: linear recurrence h = f*h + (1-f)*z is affine -> chunked parallel scan.
//    Grid (B=64, CHUNKS=32), block 256 (one thread per hidden channel).
//    Each block composes 64 steps into (A, Bv) per channel.
//  - Combine: per b, fold 32 chunk-affines sequentially, apply o (last step only),
//    dot with W_out, block-reduce -> out[b].

#define NB 64
#define NS 2048
#define NH 256
#define NG 768
#define CHUNKS 32
#define STEPS (NS / CHUNKS)   // 64

__device__ __forceinline__ float fast_sigmoid(float x) {
    // robust: exp overflow -> inf -> 1/inf = 0; underflow -> 0 -> 1/1 = 1
    return __fdividef(1.0f, 1.0f + __expf(-x));
}

__device__ __forceinline__ float fast_tanh(float x) {
    // tanh(x) = 2*sigmoid(2x) - 1 ; robust at both extremes
    float s = __fdividef(1.0f, 1.0f + __expf(-2.0f * x));
    return 2.0f * s - 1.0f;
}

__global__ __launch_bounds__(256) void precompute_kernel(
    const float* __restrict__ emb,   // [128][124]
    const float* __restrict__ Wn,    // [4][7]
    const float* __restrict__ bn,    // [4]
    const float* __restrict__ Wc,    // [768][128]
    const float* __restrict__ bc,    // [768]
    float* __restrict__ Gt,          // out [128][768]
    float* __restrict__ Wgt)         // out [7][768]
{
    int blk = blockIdx.x;
    int tid = threadIdx.x;
    if (blk < 128) {
        int e = blk;
        const float* er = emb + e * 124;
        for (int g = tid; g < NG; g += 256) {
            const float* w = Wc + g * 128;
            float acc = bc[g];
            #pragma unroll
            for (int m = 0; m < 4; ++m) acc = fmaf(w[124 + m], bn[m], acc);
            float s = 0.0f;
            #pragma unroll 4
            for (int k = 0; k < 124; ++k) s = fmaf(w[k], er[k], s);
            Gt[e * NG + g] = acc + s;
        }
    } else {
        for (int g = tid; g < NG; g += 256) {
            const float* w = Wc + g * 128 + 124;
            #pragma unroll
            for (int n = 0; n < 7; ++n) {
                float s = 0.0f;
                #pragma unroll
                for (int m = 0; m < 4; ++m) s = fmaf(w[m], Wn[m * 7 + n], s);
                Wgt[n * NG + g] = s;
            }
        }
    }
}

__global__ __launch_bounds__(256) void scan_kernel(
    const float* __restrict__ X,     // [B][S][8]
    const float* __restrict__ Gt,    // [128][768]
    const float* __restrict__ Wgt,   // [7][768]
    float* __restrict__ AB,          // [CHUNKS][B][2][256]
    float* __restrict__ Olast)       // [B][256]
{
    const int b = blockIdx.x;
    const int c = blockIdx.y;
    const int j = threadIdx.x;

    __shared__ float xs[STEPS * 8];
    const float* xsrc = X + ((size_t)b * NS + (size_t)c * STEPS) * 8;
    for (int i = j; i < STEPS * 8; i += 256) xs[i] = xsrc[i];

    float wz[7], wf[7];
    #pragma unroll
    for (int n = 0; n < 7; ++n) {
        wz[n] = Wgt[n * NG + j];
        wf[n] = Wgt[n * NG + NH + j];
    }
    __syncthreads();

    float A = 1.0f, Bv = 0.0f;
    #pragma unroll 4
    for (int t = 0; t < STEPS; ++t) {
        const int e = (int)xs[t * 8];
        const float* gr = Gt + e * NG;
        float gz = gr[j];
        float gf = gr[NH + j];
        #pragma unroll
        for (int n = 0; n < 7; ++n) {
            const float xn = xs[t * 8 + 1 + n];
            gz = fmaf(wz[n], xn, gz);
            gf = fmaf(wf[n], xn, gf);
        }
        const float z = fast_tanh(gz);
        const float f = fast_sigmoid(gf);
        A *= f;
        Bv = fmaf(f, Bv, (1.0f - f) * z);
    }

    AB[(((size_t)c * NB + b) * 2 + 0) * NH + j] = A;
    AB[(((size_t)c * NB + b) * 2 + 1) * NH + j] = Bv;

    if (c == CHUNKS - 1) {
        // o gate only matters at the global last timestep
        const int t = STEPS - 1;
        const int e = (int)xs[t * 8];
        float go = Gt[e * NG + 2 * NH + j];
        #pragma unroll
        for (int n = 0; n < 7; ++n) {
            go = fmaf(Wgt[n * NG + 2 * NH + j], xs[t * 8 + 1 + n], go);
        }
        Olast[b * NH + j] = fast_sigmoid(go);
    }
}

__global__ __launch_bounds__(256) void combine_kernel(
    const float* __restrict__ AB,     // [CHUNKS][B][2][256]
    const float* __restrict__ Olast,  // [B][256]
    const float* __restrict__ Wout,   // [1][256]
    const float* __restrict__ bout,   // [1]
    float* __restrict__ out)          // [B][1]
{
    const int b = blockIdx.x;
    const int j = threadIdx.x;

    float h = 0.0f;
    #pragma unroll 8
    for (int c = 0; c < CHUNKS; ++c) {
        const float A  = AB[(((size_t)c * NB + b) * 2 + 0) * NH + j];
        const float Bv = AB[(((size_t)c * NB + b) * 2 + 1) * NH + j];
        h = fmaf(A, h, Bv);
    }
    float v = Olast[b * NH + j] * h * Wout[j];

    // reduce 256 threads: wave64 shuffle then LDS across 4 waves
    #pragma unroll
    for (int off = 32; off > 0; off >>= 1) v += __shfl_down(v, off);
    __shared__ float red[4];
    if ((j & 63) == 0) red[j >> 6] = v;
    __syncthreads();
    if (j == 0) out[b] = red[0] + red[1] + red[2] + red[3] + bout[0];
}

extern "C" void kernel_launch(void* const* d_in, const int* in_sizes, int n_in,
                              void* d_out, int out_size, void* d_ws, size_t ws_size,
                              hipStream_t stream) {
    const float* X    = (const float*)d_in[0];
    const float* emb  = (const float*)d_in[1];
    const float* Wn   = (const float*)d_in[2];
    const float* bn   = (const float*)d_in[3];
    const float* Wc   = (const float*)d_in[4];
    const float* bc   = (const float*)d_in[5];
    const float* Wout = (const float*)d_in[6];
    const float* bout = (const float*)d_in[7];
    float* out = (float*)d_out;

    float* Gt  = (float*)d_ws;                       // 128*768
    float* Wgt = Gt + 128 * NG;                      // 7*768
    float* AB  = Wgt + 7 * NG;                       // CHUNKS*B*2*256
    float* Ol  = AB + (size_t)CHUNKS * NB * 2 * NH;  // B*256

    precompute_kernel<<<129, 256, 0, stream>>>(emb, Wn, bn, Wc, bc, Gt, Wgt);
    dim3 grid(NB, CHUNKS);
    scan_kernel<<<grid, 256, 0, stream>>>(X, Gt, Wgt, AB, Ol);
    combine_kernel<<<NB, 256, 0, stream>>>(AB, Ol, Wout, bout, out);
}

// Round 2
// 52.994 us; speedup vs baseline: 1.2700x; 1.2700x over previous
//
#include <hip/hip_runtime.h>

// QRNN fused kernel for MI355X.
// B=64, S=2048, VOCAB=128, HIDDEN=256, gates=768, emb=124, num=7.
//
//  - Precompute exp2-domain gate tables:
//      G2[e][j] = ( -2*log2e * (Wc_z[j]·[emb[e];b_num] + bc_z[j]),
//                   -1*log2e * (Wc_f[j]·[emb[e];b_num] + bc_f[j]) )
//      Wg2[n][j] = scaled numeric weights (Wc[:,124:]@W_num), Go/Wgo for o-gate.
//  - Scan: affine recurrence h = f*h + (1-f)*z  ==>  chunked parallel scan.
//    Per step: one dwordx2 table load (SGPR event index via readfirstlane),
//    7 packed fma, 2 exp2 + 2 rcp (trans pipe), 3 scan ops.
//  - Combine: fold 32 chunk affines, apply o (last step only), dot W_out.

typedef float f32x2 __attribute__((ext_vector_type(2)));

#define NB 64
#define NS 2048
#define NH 256
#define CHUNKS 32
#define STEPS (NS / CHUNKS)   // 64
#define LOG2E 1.4426950408889634f

__global__ __launch_bounds__(256) void precompute_kernel(
    const float* __restrict__ emb,   // [128][124]
    const float* __restrict__ Wn,    // [4][7]
    const float* __restrict__ bn,    // [4]
    const float* __restrict__ Wc,    // [768][128]
    const float* __restrict__ bc,    // [768]
    f32x2* __restrict__ G2,          // out [128][256]  (z', f') exp2-domain
    float* __restrict__ Go,          // out [128][256]  o'
    f32x2* __restrict__ Wg2,         // out [7][256]
    float* __restrict__ Wgo)         // out [7][256]
{
    const int tid = threadIdx.x;
    const int e = blockIdx.x;
    if (e < 128) {
        __shared__ float er[124];
        for (int i = tid; i < 124; i += 256) er[i] = emb[e * 124 + i];
        __syncthreads();
        const int j = tid;
        const float* wz = Wc + (size_t)j * 128;
        const float* wf = Wc + (size_t)(j + 256) * 128;
        const float* wo = Wc + (size_t)(j + 512) * 128;
        float az = bc[j], af = bc[j + 256], ao = bc[j + 512];
        #pragma unroll
        for (int m = 0; m < 4; ++m) {
            az = fmaf(wz[124 + m], bn[m], az);
            af = fmaf(wf[124 + m], bn[m], af);
            ao = fmaf(wo[124 + m], bn[m], ao);
        }
        #pragma unroll 4
        for (int k = 0; k < 124; ++k) {
            const float ek = er[k];
            az = fmaf(wz[k], ek, az);
            af = fmaf(wf[k], ek, af);
            ao = fmaf(wo[k], ek, ao);
        }
        G2[e * NH + j] = (f32x2){az * (-2.0f * LOG2E), af * (-LOG2E)};
        Go[e * NH + j] = ao * (-LOG2E);
    } else {
        const int j = tid;
        #pragma unroll
        for (int n = 0; n < 7; ++n) {
            float sz = 0.0f, sf = 0.0f, so = 0.0f;
            #pragma unroll
            for (int m = 0; m < 4; ++m) {
                const float wnm = Wn[m * 7 + n];
                sz = fmaf(Wc[(size_t)j * 128 + 124 + m], wnm, sz);
                sf = fmaf(Wc[(size_t)(j + 256) * 128 + 124 + m], wnm, sf);
                so = fmaf(Wc[(size_t)(j + 512) * 128 + 124 + m], wnm, so);
            }
            Wg2[n * NH + j] = (f32x2){sz * (-2.0f * LOG2E), sf * (-LOG2E)};
            Wgo[n * NH + j] = so * (-LOG2E);
        }
    }
}

__global__ __launch_bounds__(256) void scan_kernel(
    const float* __restrict__ X,     // [B][S][8]
    const f32x2* __restrict__ G2,    // [128][256]
    const float* __restrict__ Go,    // [128][256]
    const f32x2* __restrict__ Wg2,   // [7][256]
    const float* __restrict__ Wgo,   // [7][256]
    float* __restrict__ AB,          // [CHUNKS][B][2][256]
    float* __restrict__ Olast)       // [B][256]
{
    const int b = blockIdx.x;
    const int c = blockIdx.y;
    const int j = threadIdx.x;

    __shared__ float xs[STEPS * 8];
    const float* xsrc = X + ((size_t)b * NS + (size_t)c * STEPS) * 8;
    for (int i = j; i < STEPS * 8; i += 256) xs[i] = xsrc[i];

    f32x2 w2[7];
    #pragma unroll
    for (int n = 0; n < 7; ++n) w2[n] = Wg2[n * NH + j];
    __syncthreads();

    float A = 1.0f, Bv = 0.0f;
    #pragma unroll 8
    for (int t = 0; t < STEPS; ++t) {
        const int e = __builtin_amdgcn_readfirstlane((int)xs[t * 8]);
        f32x2 g2 = G2[e * NH + j];
        #pragma unroll
        for (int n = 0; n < 7; ++n) {
            const float xn = xs[t * 8 + 1 + n];
            g2 = __builtin_elementwise_fma(w2[n], (f32x2){xn, xn}, g2);
        }
        const float ez = __builtin_amdgcn_exp2f(g2.x);   // exp(-2 gz)
        const float ef = __builtin_amdgcn_exp2f(g2.y);   // exp(-gf)
        const float z = fmaf(2.0f, __builtin_amdgcn_rcpf(1.0f + ez), -1.0f);
        const float f = __builtin_amdgcn_rcpf(1.0f + ef);
        A *= f;
        Bv = fmaf(f, Bv - z, z);   // z + f*(Bv - z)
    }

    AB[(((size_t)c * NB + b) * 2 + 0) * NH + j] = A;
    AB[(((size_t)c * NB + b) * 2 + 1) * NH + j] = Bv;

    if (c == CHUNKS - 1) {
        const int t = STEPS - 1;
        const int e = __builtin_amdgcn_readfirstlane((int)xs[t * 8]);
        float go = Go[e * NH + j];
        #pragma unroll
        for (int n = 0; n < 7; ++n) {
            go = fmaf(Wgo[n * NH + j], xs[t * 8 + 1 + n], go);
        }
        Olast[b * NH + j] = __builtin_amdgcn_rcpf(1.0f + __builtin_amdgcn_exp2f(go));
    }
}

__global__ __launch_bounds__(256) void combine_kernel(
    const float* __restrict__ AB,     // [CHUNKS][B][2][256]
    const float* __restrict__ Olast,  // [B][256]
    const float* __restrict__ Wout,   // [1][256]
    const float* __restrict__ bout,   // [1]
    float* __restrict__ out)          // [B][1]
{
    const int b = blockIdx.x;
    const int j = threadIdx.x;

    float h = 0.0f;
    #pragma unroll 8
    for (int c = 0; c < CHUNKS; ++c) {
        const float A  = AB[(((size_t)c * NB + b) * 2 + 0) * NH + j];
        const float Bv = AB[(((size_t)c * NB + b) * 2 + 1) * NH + j];
        h = fmaf(A, h, Bv);
    }
    float v = Olast[b * NH + j] * h * Wout[j];

    #pragma unroll
    for (int off = 32; off > 0; off >>= 1) v += __shfl_down(v, off);
    __shared__ float red[4];
    if ((j & 63) == 0) red[j >> 6] = v;
    __syncthreads();
    if (j == 0) out[b] = red[0] + red[1] + red[2] + red[3] + bout[0];
}

extern "C" void kernel_launch(void* const* d_in, const int* in_sizes, int n_in,
                              void* d_out, int out_size, void* d_ws, size_t ws_size,
                              hipStream_t stream) {
    const float* X    = (const float*)d_in[0];
    const float* emb  = (const float*)d_in[1];
    const float* Wn   = (const float*)d_in[2];
    const float* bn   = (const float*)d_in[3];
    const float* Wc   = (const float*)d_in[4];
    const float* bc   = (const float*)d_in[5];
    const float* Wout = (const float*)d_in[6];
    const float* bout = (const float*)d_in[7];
    float* out = (float*)d_out;

    f32x2* G2  = (f32x2*)d_ws;                        // 128*256 f32x2
    float* Go  = (float*)(G2 + 128 * NH);             // 128*256
    f32x2* Wg2 = (f32x2*)(Go + 128 * NH);             // 7*256 f32x2
    float* Wgo = (float*)(Wg2 + 7 * NH);              // 7*256
    float* AB  = Wgo + 7 * NH;                        // 32*64*2*256
    float* Ol  = AB + (size_t)CHUNKS * NB * 2 * NH;   // 64*256

    precompute_kernel<<<129, 256, 0, stream>>>(emb, Wn, bn, Wc, bc, G2, Go, Wg2, Wgo);
    dim3 grid(NB, CHUNKS);
    scan_kernel<<<grid, 256, 0, stream>>>(X, G2, Go, Wg2, Wgo, AB, Ol);
    combine_kernel<<<NB, 256, 0, stream>>>(AB, Ol, Wout, bout, out);
}

// Round 3
// 49.932 us; speedup vs baseline: 1.3479x; 1.0613x over previous
//
#include <hip/hip_runtime.h>

// QRNN fused kernel for MI355X.
// B=64, S=2048, VOCAB=128, HIDDEN=256, gates=768, emb=124, num=7.
//
//  - Precompute exp2-domain gate tables:
//      G2[e][j] = ( -2*log2e * z_row, -1*log2e * f_row ),  Go[e][j] = -log2e * o_row
//      Wg2[n][j] / Wgo[n][j] = numeric-path weights folded through W_num, same scaling.
//  - Scan: affine recurrence h = f*h + (1-f)*z  ==>  chunked parallel scan.
//    NO LDS: x rows are block-uniform -> uniform global loads promote to s_load
//    (SMEM pipe), freeing the LDS pipe that bottlenecked round 1/2 (8 ds_read_b32
//    per step x 32 waves/CU saturated the per-CU LDS pipe ~= 40us).
//    Per step: 0.5 s_load_dwordx16, 1 global_load_dwordx2 (saddr, invariant voffset),
//    7 v_pk_fma_f32, 2 exp2 + 2 rcp (trans), ~6 scalar-ish VALU.
//  - Combine: fold 32 chunk affines, apply o (last step only), dot W_out.

typedef float f32x2 __attribute__((ext_vector_type(2)));
typedef float f32x4 __attribute__((ext_vector_type(4)));

#define NB 64
#define NS 2048
#define NH 256
#define CHUNKS 32
#define STEPS (NS / CHUNKS)   // 64
#define LOG2E 1.4426950408889634f

__global__ __launch_bounds__(256) void precompute_kernel(
    const float* __restrict__ emb,   // [128][124]
    const float* __restrict__ Wn,    // [4][7]
    const float* __restrict__ bn,    // [4]
    const float* __restrict__ Wc,    // [768][128]
    const float* __restrict__ bc,    // [768]
    f32x2* __restrict__ G2,          // out [128][256]  (z', f') exp2-domain
    float* __restrict__ Go,          // out [128][256]  o'
    f32x2* __restrict__ Wg2,         // out [7][256]
    float* __restrict__ Wgo)         // out [7][256]
{
    const int tid = threadIdx.x;
    const int e = blockIdx.x;
    if (e < 128) {
        __shared__ float er[124];
        for (int i = tid; i < 124; i += 256) er[i] = emb[e * 124 + i];
        __syncthreads();
        const int j = tid;
        const float* wz = Wc + (size_t)j * 128;
        const float* wf = Wc + (size_t)(j + 256) * 128;
        const float* wo = Wc + (size_t)(j + 512) * 128;
        float az = bc[j], af = bc[j + 256], ao = bc[j + 512];
        #pragma unroll
        for (int m = 0; m < 4; ++m) {
            az = fmaf(wz[124 + m], bn[m], az);
            af = fmaf(wf[124 + m], bn[m], af);
            ao = fmaf(wo[124 + m], bn[m], ao);
        }
        #pragma unroll 4
        for (int k = 0; k < 124; ++k) {
            const float ek = er[k];
            az = fmaf(wz[k], ek, az);
            af = fmaf(wf[k], ek, af);
            ao = fmaf(wo[k], ek, ao);
        }
        G2[e * NH + j] = (f32x2){az * (-2.0f * LOG2E), af * (-LOG2E)};
        Go[e * NH + j] = ao * (-LOG2E);
    } else {
        const int j = tid;
        #pragma unroll
        for (int n = 0; n < 7; ++n) {
            float sz = 0.0f, sf = 0.0f, so = 0.0f;
            #pragma unroll
            for (int m = 0; m < 4; ++m) {
                const float wnm = Wn[m * 7 + n];
                sz = fmaf(Wc[(size_t)j * 128 + 124 + m], wnm, sz);
                sf = fmaf(Wc[(size_t)(j + 256) * 128 + 124 + m], wnm, sf);
                so = fmaf(Wc[(size_t)(j + 512) * 128 + 124 + m], wnm, so);
            }
            Wg2[n * NH + j] = (f32x2){sz * (-2.0f * LOG2E), sf * (-LOG2E)};
            Wgo[n * NH + j] = so * (-LOG2E);
        }
    }
}

__global__ __launch_bounds__(256) void scan_kernel(
    const float* __restrict__ X,     // [B][S][8]
    const f32x2* __restrict__ G2,    // [128][256]
    const float* __restrict__ Go,    // [128][256]
    const f32x2* __restrict__ Wg2,   // [7][256]
    const float* __restrict__ Wgo,   // [7][256]
    float* __restrict__ AB,          // [CHUNKS][B][2][256]
    float* __restrict__ Olast)       // [B][256]
{
    const int b = blockIdx.x;
    const int c = blockIdx.y;
    const int j = threadIdx.x;

    // block-uniform x pointer: loads below have uniform addresses -> SMEM
    const f32x4* __restrict__ xp =
        (const f32x4*)(X + ((size_t)b * NS + (size_t)c * STEPS) * 8);

    f32x2 w2[7];
    #pragma unroll
    for (int n = 0; n < 7; ++n) w2[n] = Wg2[n * NH + j];

    float A = 1.0f, Bv = 0.0f;
    #pragma unroll 8
    for (int t = 0; t < STEPS; ++t) {
        const f32x4 xa = xp[2 * t];      // [event, x0, x1, x2]
        const f32x4 xb = xp[2 * t + 1];  // [x3, x4, x5, x6]
        const int e = __builtin_amdgcn_readfirstlane((int)xa.x);
        f32x2 g2 = G2[e * NH + j];
        g2 = __builtin_elementwise_fma(w2[0], (f32x2){xa.y, xa.y}, g2);
        g2 = __builtin_elementwise_fma(w2[1], (f32x2){xa.z, xa.z}, g2);
        g2 = __builtin_elementwise_fma(w2[2], (f32x2){xa.w, xa.w}, g2);
        g2 = __builtin_elementwise_fma(w2[3], (f32x2){xb.x, xb.x}, g2);
        g2 = __builtin_elementwise_fma(w2[4], (f32x2){xb.y, xb.y}, g2);
        g2 = __builtin_elementwise_fma(w2[5], (f32x2){xb.z, xb.z}, g2);
        g2 = __builtin_elementwise_fma(w2[6], (f32x2){xb.w, xb.w}, g2);
        const float ez = __builtin_amdgcn_exp2f(g2.x);   // exp(-2 gz)
        const float ef = __builtin_amdgcn_exp2f(g2.y);   // exp(-gf)
        const float z = fmaf(2.0f, __builtin_amdgcn_rcpf(1.0f + ez), -1.0f);
        const float f = __builtin_amdgcn_rcpf(1.0f + ef);
        A *= f;
        Bv = fmaf(f, Bv - z, z);   // z + f*(Bv - z)
    }

    AB[(((size_t)c * NB + b) * 2 + 0) * NH + j] = A;
    AB[(((size_t)c * NB + b) * 2 + 1) * NH + j] = Bv;

    if (c == CHUNKS - 1) {
        const int t = STEPS - 1;
        const f32x4 xa = xp[2 * t];
        const f32x4 xb = xp[2 * t + 1];
        const int e = __builtin_amdgcn_readfirstlane((int)xa.x);
        float go = Go[e * NH + j];
        go = fmaf(Wgo[0 * NH + j], xa.y, go);
        go = fmaf(Wgo[1 * NH + j], xa.z, go);
        go = fmaf(Wgo[2 * NH + j], xa.w, go);
        go = fmaf(Wgo[3 * NH + j], xb.x, go);
        go = fmaf(Wgo[4 * NH + j], xb.y, go);
        go = fmaf(Wgo[5 * NH + j], xb.z, go);
        go = fmaf(Wgo[6 * NH + j], xb.w, go);
        Olast[b * NH + j] = __builtin_amdgcn_rcpf(1.0f + __builtin_amdgcn_exp2f(go));
    }
}

__global__ __launch_bounds__(256) void combine_kernel(
    const float* __restrict__ AB,     // [CHUNKS][B][2][256]
    const float* __restrict__ Olast,  // [B][256]
    const float* __restrict__ Wout,   // [1][256]
    const float* __restrict__ bout,   // [1]
    float* __restrict__ out)          // [B][1]
{
    const int b = blockIdx.x;
    const int j = threadIdx.x;

    float h = 0.0f;
    #pragma unroll 8
    for (int c = 0; c < CHUNKS; ++c) {
        const float A  = AB[(((size_t)c * NB + b) * 2 + 0) * NH + j];
        const float Bv = AB[(((size_t)c * NB + b) * 2 + 1) * NH + j];
        h = fmaf(A, h, Bv);
    }
    float v = Olast[b * NH + j] * h * Wout[j];

    #pragma unroll
    for (int off = 32; off > 0; off >>= 1) v += __shfl_down(v, off);
    __shared__ float red[4];
    if ((j & 63) == 0) red[j >> 6] = v;
    __syncthreads();
    if (j == 0) out[b] = red[0] + red[1] + red[2] + red[3] + bout[0];
}

extern "C" void kernel_launch(void* const* d_in, const int* in_sizes, int n_in,
                              void* d_out, int out_size, void* d_ws, size_t ws_size,
                              hipStream_t stream) {
    const float* X    = (const float*)d_in[0];
    const float* emb  = (const float*)d_in[1];
    const float* Wn   = (const float*)d_in[2];
    const float* bn   = (const float*)d_in[3];
    const float* Wc   = (const float*)d_in[4];
    const float* bc   = (const float*)d_in[5];
    const float* Wout = (const float*)d_in[6];
    const float* bout = (const float*)d_in[7];
    float* out = (float*)d_out;

    f32x2* G2  = (f32x2*)d_ws;                        // 128*256 f32x2
    float* Go  = (float*)(G2 + 128 * NH);             // 128*256
    f32x2* Wg2 = (f32x2*)(Go + 128 * NH);             // 7*256 f32x2
    float* Wgo = (float*)(Wg2 + 7 * NH);              // 7*256
    float* AB  = Wgo + 7 * NH;                        // 32*64*2*256
    float* Ol  = AB + (size_t)CHUNKS * NB * 2 * NH;   // 64*256

    precompute_kernel<<<129, 256, 0, stream>>>(emb, Wn, bn, Wc, bc, G2, Go, Wg2, Wgo);
    dim3 grid(NB, CHUNKS);
    scan_kernel<<<grid, 256, 0, stream>>>(X, G2, Go, Wg2, Wgo, AB, Ol);
    combine_kernel<<<NB, 256, 0, stream>>>(AB, Ol, Wout, bout, out);
}

// Round 4
// 40.905 us; speedup vs baseline: 1.6454x; 1.2207x over previous
//
#include <hip/hip_runtime.h>

// QRNN fused kernel for MI355X.
// B=64, S=2048, VOCAB=128, HIDDEN=256, gates=768, emb=124, num=7.
//
//  - precompute_kernel (one grid, three roles):
//      blocks 0..63   : GEMM  G[768][128e] = Wc[:, :124] @ emb^T  (emb^T staged in
//                       LDS, pad 129 -> conflict-free), b_num folded via bias path.
//                       Writes exp2-domain tables G2[e][j]=(z',f'), Go[e][j]=o'.
//      block  64      : Wg2/Wgo numeric-path weights (Wc[:,124:] @ W_num, scaled).
//      blocks 65..192 : event extraction Eoff[b*S+t] = ((int)X[...,0]) << 11
//                       (byte offset of G2 row; kills the per-step cvt/readfirstlane
//                       address chain that serialized the scan).
//  - scan_kernel: affine recurrence h = f*h + (1-f)*z, chunked scan (32 chunks x 64).
//      Per step: s_load event offset (batched dwordx8) + s_load x numerics,
//      1 v_add + global_load_dwordx2 (saddr form), 7 v_pk_fma_f32,
//      2 exp2 + 2 rcp (trans pipe), 3-op scan update. Deep cross-step ILP:
//      no per-step VALU->SGPR round trip.
//  - combine_kernel: fold 32 chunk affines, apply o (last step only), dot W_out.

typedef float f32x2 __attribute__((ext_vector_type(2)));
typedef float f32x4 __attribute__((ext_vector_type(4)));

#define NB 64
#define NS 2048
#define NH 256
#define CHUNKS 32
#define STEPS (NS / CHUNKS)   // 64
#define LOG2E 1.4426950408889634f
#define PAD 129

__global__ __launch_bounds__(256) void precompute_kernel(
    const float* __restrict__ X,     // [B][S][8]
    const float* __restrict__ emb,   // [128][124]
    const float* __restrict__ Wn,    // [4][7]
    const float* __restrict__ bn,    // [4]
    const float* __restrict__ Wc,    // [768][128]
    const float* __restrict__ bc,    // [768]
    f32x2* __restrict__ G2,          // out [128e][256j]  (z', f') exp2-domain
    float* __restrict__ Go,          // out [128e][256j]  o'
    f32x2* __restrict__ Wg2,         // out [7][256]
    float* __restrict__ Wgo,         // out [7][256]
    int*   __restrict__ Eoff)        // out [B*S] byte offsets e*2048
{
    __shared__ float M[124 * PAD];   // emb^T staged: M[k*PAD + e] = emb[e][k]
    const int tid = threadIdx.x;
    const int blk = blockIdx.x;

    if (blk < 64) {
        // ---- stage emb^T into LDS (coalesced f32x4 reads, conflict-free writes)
        {
            const int e = tid >> 1, half = tid & 1;
            const f32x4* er4 = (const f32x4*)(emb + (size_t)e * 124);  // 124*4B = 31 x16B, 16B-aligned
            #pragma unroll
            for (int i = 0; i < 16; ++i) {
                const int idx = half * 16 + i;
                if (idx < 31) {
                    const f32x4 v = er4[idx];
                    const int k0 = idx * 4;
                    M[(k0 + 0) * PAD + e] = v.x;
                    M[(k0 + 1) * PAD + e] = v.y;
                    M[(k0 + 2) * PAD + e] = v.z;
                    M[(k0 + 3) * PAD + e] = v.w;
                }
            }
        }
        __syncthreads();

        const int e = tid & 127;
        const int s = tid >> 7;
        const int j0 = blk * 4 + s * 2;   // this thread: j0, j0+1

        float bnv[4];
        #pragma unroll
        for (int m = 0; m < 4; ++m) bnv[m] = bn[m];

        float acc[2][3] = {{0.f,0.f,0.f},{0.f,0.f,0.f}};
        const f32x4* wz4[2]; const f32x4* wf4[2]; const f32x4* wo4[2];
        #pragma unroll
        for (int i = 0; i < 2; ++i) {
            wz4[i] = (const f32x4*)(Wc + (size_t)(j0 + i) * 128);
            wf4[i] = (const f32x4*)(Wc + (size_t)(j0 + i + 256) * 128);
            wo4[i] = (const f32x4*)(Wc + (size_t)(j0 + i + 512) * 128);
        }

        for (int kb = 0; kb < 31; ++kb) {
            f32x4 w[2][3];
            #pragma unroll
            for (int i = 0; i < 2; ++i) {
                w[i][0] = wz4[i][kb];
                w[i][1] = wf4[i][kb];
                w[i][2] = wo4[i][kb];
            }
            #pragma unroll
            for (int u = 0; u < 4; ++u) {
                const float mv = M[(kb * 4 + u) * PAD + e];
                #pragma unroll
                for (int i = 0; i < 2; ++i) {
                    acc[i][0] = fmaf(w[i][0][u], mv, acc[i][0]);
                    acc[i][1] = fmaf(w[i][1][u], mv, acc[i][1]);
                    acc[i][2] = fmaf(w[i][2][u], mv, acc[i][2]);
                }
            }
        }

        #pragma unroll
        for (int i = 0; i < 2; ++i) {
            const int j = j0 + i;
            float az = acc[i][0] + bc[j];
            float af = acc[i][1] + bc[j + 256];
            float ao = acc[i][2] + bc[j + 512];
            const f32x4 tz = wz4[i][31];
            const f32x4 tf = wf4[i][31];
            const f32x4 to = wo4[i][31];
            #pragma unroll
            for (int m = 0; m < 4; ++m) {
                az = fmaf(tz[m], bnv[m], az);
                af = fmaf(tf[m], bnv[m], af);
                ao = fmaf(to[m], bnv[m], ao);
            }
            G2[(size_t)e * NH + j] = (f32x2){az * (-2.0f * LOG2E), af * (-LOG2E)};
            Go[(size_t)e * NH + j] = ao * (-LOG2E);
        }
    } else if (blk == 64) {
        const int j = tid;
        #pragma unroll
        for (int n = 0; n < 7; ++n) {
            float sz = 0.0f, sf = 0.0f, so = 0.0f;
            #pragma unroll
            for (int m = 0; m < 4; ++m) {
                const float wnm = Wn[m * 7 + n];
                sz = fmaf(Wc[(size_t)j * 128 + 124 + m], wnm, sz);
                sf = fmaf(Wc[(size_t)(j + 256) * 128 + 124 + m], wnm, sf);
                so = fmaf(Wc[(size_t)(j + 512) * 128 + 124 + m], wnm, so);
            }
            Wg2[n * NH + j] = (f32x2){sz * (-2.0f * LOG2E), sf * (-LOG2E)};
            Wgo[n * NH + j] = so * (-LOG2E);
        }
    } else {
        // event extraction: 128 blocks x 1024 events
        const int base = (blk - 65) * 1024 + tid;
        #pragma unroll
        for (int u = 0; u < 4; ++u) {
            const int idx = base + u * 256;
            Eoff[idx] = ((int)X[(size_t)idx * 8]) << 11;   // e * 2048 bytes
        }
    }
}

__global__ __launch_bounds__(256) void scan_kernel(
    const float* __restrict__ X,     // [B][S][8]
    const int* __restrict__ Eoff,    // [B*S]
    const f32x2* __restrict__ G2,    // [128][256]
    const float* __restrict__ Go,    // [128][256]
    const f32x2* __restrict__ Wg2,   // [7][256]
    const float* __restrict__ Wgo,   // [7][256]
    float* __restrict__ AB,          // [CHUNKS][B][2][256]
    float* __restrict__ Olast)       // [B][256]
{
    const int b = blockIdx.x;
    const int c = blockIdx.y;
    const int j = threadIdx.x;

    const int*   __restrict__ ep = Eoff + b * NS + c * STEPS;                 // uniform
    const float* __restrict__ xp = X + ((size_t)b * NS + (size_t)c * STEPS) * 8; // uniform
    const char*  __restrict__ g2b = (const char*)G2;
    const char*  __restrict__ gob = (const char*)Go;
    const int j8 = j * 8;

    f32x2 w2[7];
    #pragma unroll
    for (int n = 0; n < 7; ++n) w2[n] = Wg2[n * NH + j];

    float A = 1.0f, Bv = 0.0f;
    #pragma unroll 8
    for (int t = 0; t < STEPS; ++t) {
        const int eo = ep[t];                                   // s_load, batched
        f32x2 g2 = *(const f32x2*)(g2b + eo + j8);              // saddr + voffset
        #pragma unroll
        for (int n = 0; n < 7; ++n) {
            const float xn = xp[t * 8 + 1 + n];                 // s_load, batched
            g2 = __builtin_elementwise_fma(w2[n], (f32x2){xn, xn}, g2);
        }
        const float ez = __builtin_amdgcn_exp2f(g2.x);          // exp(-2 gz)
        const float ef = __builtin_amdgcn_exp2f(g2.y);          // exp(-gf)
        const float z = fmaf(2.0f, __builtin_amdgcn_rcpf(1.0f + ez), -1.0f);
        const float f = __builtin_amdgcn_rcpf(1.0f + ef);
        A *= f;
        Bv = fmaf(f, Bv - z, z);   // z + f*(Bv - z)
    }

    AB[(((size_t)c * NB + b) * 2 + 0) * NH + j] = A;
    AB[(((size_t)c * NB + b) * 2 + 1) * NH + j] = Bv;

    if (c == CHUNKS - 1) {
        const int t = STEPS - 1;
        const int eo = ep[t];
        float go = *(const float*)(gob + (eo >> 1) + j * 4);
        #pragma unroll
        for (int n = 0; n < 7; ++n) {
            go = fmaf(Wgo[n * NH + j], xp[t * 8 + 1 + n], go);
        }
        Olast[b * NH + j] = __builtin_amdgcn_rcpf(1.0f + __builtin_amdgcn_exp2f(go));
    }
}

__global__ __launch_bounds__(256) void combine_kernel(
    const float* __restrict__ AB,     // [CHUNKS][B][2][256]
    const float* __restrict__ Olast,  // [B][256]
    const float* __restrict__ Wout,   // [1][256]
    const float* __restrict__ bout,   // [1]
    float* __restrict__ out)          // [B][1]
{
    const int b = blockIdx.x;
    const int j = threadIdx.x;

    float h = 0.0f;
    #pragma unroll 8
    for (int c = 0; c < CHUNKS; ++c) {
        const float A  = AB[(((size_t)c * NB + b) * 2 + 0) * NH + j];
        const float Bv = AB[(((size_t)c * NB + b) * 2 + 1) * NH + j];
        h = fmaf(A, h, Bv);
    }
    float v = Olast[b * NH + j] * h * Wout[j];

    #pragma unroll
    for (int off = 32; off > 0; off >>= 1) v += __shfl_down(v, off);
    __shared__ float red[4];
    if ((j & 63) == 0) red[j >> 6] = v;
    __syncthreads();
    if (j == 0) out[b] = red[0] + red[1] + red[2] + red[3] + bout[0];
}

extern "C" void kernel_launch(void* const* d_in, const int* in_sizes, int n_in,
                              void* d_out, int out_size, void* d_ws, size_t ws_size,
                              hipStream_t stream) {
    const float* X    = (const float*)d_in[0];
    const float* emb  = (const float*)d_in[1];
    const float* Wn   = (const float*)d_in[2];
    const float* bn   = (const float*)d_in[3];
    const float* Wc   = (const float*)d_in[4];
    const float* bc   = (const float*)d_in[5];
    const float* Wout = (const float*)d_in[6];
    const float* bout = (const float*)d_in[7];
    float* out = (float*)d_out;

    f32x2* G2  = (f32x2*)d_ws;                        // 128*256 f32x2 (256 KB)
    float* Go  = (float*)(G2 + 128 * NH);             // 128*256     (128 KB)
    f32x2* Wg2 = (f32x2*)(Go + 128 * NH);             // 7*256 f32x2
    float* Wgo = (float*)(Wg2 + 7 * NH);              // 7*256
    float* AB  = Wgo + 7 * NH;                        // 32*64*2*256 (4 MB)
    float* Ol  = AB + (size_t)CHUNKS * NB * 2 * NH;   // 64*256
    int*   Eo  = (int*)(Ol + NB * NH);                // 64*2048 ints (512 KB)

    precompute_kernel<<<193, 256, 0, stream>>>(X, emb, Wn, bn, Wc, bc,
                                               G2, Go, Wg2, Wgo, Eo);
    dim3 grid(NB, CHUNKS);
    scan_kernel<<<grid, 256, 0, stream>>>(X, Eo, G2, Go, Wg2, Wgo, AB, Ol);
    combine_kernel<<<NB, 256, 0, stream>>>(AB, Ol, Wout, bout, out);
}